// Round 11
// baseline (96.867 us; speedup 1.0000x reference)
//
#include <hip/hip_runtime.h>
#include <math.h>

// CoordinateDecoder via f16 MFMA (v_mfma_f32_32x32x16_f16).
// R11 = R10 with the wave-stride bug fixed: a wave covers 32*NT=128 px, so
// wave stride is 128 (was wrongly 256 -> half the pixels unwritten).
// Latency-bound decoder -> widen per-wave ILP: NT=4 pixel tiles, 8
// independent MFMAs per kt step, fragment loads amortized, wave count
// halved; VGPR ~240 -> 2 waves/SIMD (deliberate TLP->ILP trade).
// k-axis permutation trick: pi(16kt+8q+reg)=32(kt>>1)+16(kt&1)+8(reg>>2)+4q+(reg&3)
// makes C/D register layout == next layer's B-fragment layout (no cross-lane
// ops). sqrt(2) folded into next-layer weights; cond halves precomputed as
// fp32 accumulator-init biases by prep_kernel.

typedef _Float16 half2v __attribute__((ext_vector_type(2)));
typedef __fp16   fp16x2 __attribute__((ext_vector_type(2)));
typedef _Float16 half4v __attribute__((ext_vector_type(4)));
typedef _Float16 half8  __attribute__((ext_vector_type(8)));
typedef float f32x16 __attribute__((ext_vector_type(16)));

#define SCALE1 0.0790569415042094833f  // 1/sqrt(160)
#define SCALE2 0.0721687836487032206f  // 1/sqrt(192)
#define SQRT2F 1.41421356237309515f

// fragment region: half8 entries (16B each). tile entry = (mt*Kt+kt)*64+lane
#define FE_L1 0      // Mt=2, Kt=2 -> 4*64
#define FE_L2 256    // Mt=2, Kt=4 -> 8*64
#define FE_L3 768    // Mt=2, Kt=4 -> 8*64
#define FE_L4 1280   // Mt=1, Kt=4 -> 4*64 (rows j>=4 zeroed)
#define OFF_CB1 6144   // [8][64] fp32 cond bias (incl b1)
#define OFF_CB2 6656
#define OFF_CB3 7168
#define OFF_CB4 7680   // [8][4]

__global__ __launch_bounds__(256) void prep_kernel(
    const float* __restrict__ c, const float* __restrict__ fu,
    const float* __restrict__ w1, const float* __restrict__ b1,
    const float* __restrict__ w2, const float* __restrict__ b2,
    const float* __restrict__ w3, const float* __restrict__ b3,
    const float* __restrict__ w4, const float* __restrict__ b4,
    float* __restrict__ ws)
{
  int t = blockIdx.x * 256 + threadIdx.x;
  if (t < 12288) {
    // weight A-fragment packing, f16
    _Float16* fr = (_Float16*)ws;
    int e, Ktm;
    const float* w; float scale; int stride; bool perm;
    if (t < 2048)       { e = t;         Ktm = 2; w = w1; scale = SCALE1;          stride = 160; perm = false; }
    else if (t < 6144)  { e = t - 2048;  Ktm = 4; w = w2; scale = SCALE2 * SQRT2F; stride = 192; perm = true;  }
    else if (t < 10240) { e = t - 6144;  Ktm = 4; w = w3; scale = SCALE2 * SQRT2F; stride = 192; perm = true;  }
    else                { e = t - 10240; Ktm = 4; w = w4; scale = SCALE2 * SQRT2F; stride = 192; perm = true;  }
    int til  = e >> 9;           // (mt*Kt+kt)
    int lane = (e >> 3) & 63;
    int r    = e & 7;            // reg within half8
    int q    = lane >> 5;
    int mt = til / Ktm, kt = til - mt * Ktm;
    int j = 32 * mt + (lane & 31);
    int k;
    if (perm) {
      k = 32 * (kt >> 1) + 16 * (kt & 1) + 8 * (r >> 2) + 4 * q + (r & 3);
    } else {
      k = 16 * kt + 8 * q + r;   // layer-1 embedding order (identity)
    }
    float val;
    if (t < 2048) {
      float mw = (fu[0] - (float)((k >> 2) + 1) * (1.0f / 9.0f)) * 9.0f;
      mw = fminf(fmaxf(mw, 0.0f), 1.0f);
      val = w[j * stride + k] * scale * mw;
    } else if (t >= 10240) {
      val = (j < 4) ? w[j * stride + k] * scale : 0.0f;  // mt==0 only
    } else {
      val = w[j * stride + k] * scale;
    }
    fr[t] = (_Float16)val;
  } else if (t < 12288 + 2048) {
    // per-(batch, output) conditioning dot products (fp32), wave-uniform
    int u = t - 12288;
    int grp = u >> 9;
    const float* wr; float bias; float scale; int outoff;
    int b, j;
    if (grp < 3) {
      b = (u & 511) >> 6; j = u & 63;
      if (grp == 0)      { wr = w1 + j * 160 + 32; bias = b1[j]; scale = SCALE1; outoff = OFF_CB1 + b * 64 + j; }
      else if (grp == 1) { wr = w2 + j * 192 + 64; bias = b2[j]; scale = SCALE2; outoff = OFF_CB2 + b * 64 + j; }
      else               { wr = w3 + j * 192 + 64; bias = b3[j]; scale = SCALE2; outoff = OFF_CB3 + b * 64 + j; }
    } else {
      int u2 = u - 1536;
      if (u2 >= 32) return;
      b = u2 >> 2; j = u2 & 3;
      wr = w4 + j * 192 + 64; bias = b4[j]; scale = SCALE2; outoff = OFF_CB4 + b * 4 + j;
    }
    const float4* wv = (const float4*)wr;
    const float4* cv = (const float4*)(c + b * 128);
    float4 s = make_float4(0.f, 0.f, 0.f, 0.f);
    #pragma unroll
    for (int k = 0; k < 32; ++k) {
      float4 a = wv[k], d = cv[k];
      s.x = fmaf(a.x, d.x, s.x);
      s.y = fmaf(a.y, d.y, s.y);
      s.z = fmaf(a.z, d.z, s.z);
      s.w = fmaf(a.w, d.w, s.w);
    }
    float dot = (s.x + s.y) + (s.z + s.w);
    ws[outoff] = fmaf(scale, dot, bias);
  }
}

#define NT 4  // 32-px tiles per wave -> 128 px/wave

__global__ __launch_bounds__(256, 2) void decoder_main(
    const float2* __restrict__ coords, const float* __restrict__ ws,
    float4* __restrict__ out)
{
  const int lane = threadIdx.x & 63;
  const int wave = threadIdx.x >> 6;
  // wave covers 32*NT = 128 px; block = 4 waves = 512 px
  const int base = blockIdx.x * (32 * NT * 4) + wave * (32 * NT);
  const int b    = base >> 16;                    // batch image (block-uniform)
  const int col  = lane & 31;
  const bool hi  = lane >= 32;                    // q = lane>>5
  const int q4   = hi ? 4 : 0;

  const half8* __restrict__ frags = (const half8*)ws;
  const float* __restrict__ cb1 = ws + OFF_CB1 + b * 64;
  const float* __restrict__ cb2 = ws + OFF_CB2 + b * 64;
  const float* __restrict__ cb3 = ws + OFF_CB3 + b * 64;
  const float* __restrict__ cb4 = ws + OFF_CB4 + b * 4;

  int px[NT];
  float2 cc[NT];
  #pragma unroll
  for (int nt = 0; nt < NT; ++nt) {
    px[nt] = base + 32 * nt + col;
    cc[nt] = coords[px[nt]];
  }

  // ---- layer-1 B fragments: sinusoidal embedding via double-angle chain --
  // lane needs freqs 2q+{0,1,4,5}: 2 transcendentals + 5 doublings per
  // axis-pixel. s'=2sc, c'=(c-s)(c+s). Packed f16 cvt via cvt_pkrtz.
  half8 bf[NT][2];  // [nt][kt]
  {
    const float qm = hi ? 0.4f : 0.1f;  // 0.1 * 2^(2q)
    auto chain = [](float a, float* s, float* c) {
      float s0 = __sinf(a), c0 = __cosf(a);
      s[0] = s0; c[0] = c0;
      float s1 = 2.f * s0 * c0, c1 = (c0 - s0) * (c0 + s0);
      s[1] = s1; c[1] = c1;
      float s2 = 2.f * s1 * c1, c2 = (c1 - s1) * (c1 + s1);
      float s3 = 2.f * s2 * c2, c3 = (c2 - s2) * (c2 + s2);
      float s4 = 2.f * s3 * c3, c4 = (c3 - s3) * (c3 + s3);
      s[2] = s4; c[2] = c4;
      float s5 = 2.f * s4 * c4, c5 = (c4 - s4) * (c4 + s4);
      s[3] = s5; c[3] = c5;
    };
    #pragma unroll
    for (int nt = 0; nt < NT; ++nt) {
      float sx[4], cx[4], sy[4], cy[4];
      chain(cc[nt].x * qm, sx, cx);
      chain(cc[nt].y * qm, sy, cy);
      #pragma unroll
      for (int kt = 0; kt < 2; ++kt) {
        const int i0 = 2 * kt, i1 = 2 * kt + 1;
        half2v p0 = __builtin_bit_cast(half2v, __builtin_amdgcn_cvt_pkrtz(sx[i0], sy[i0]));
        half2v p1 = __builtin_bit_cast(half2v, __builtin_amdgcn_cvt_pkrtz(cx[i0], cy[i0]));
        half2v p2 = __builtin_bit_cast(half2v, __builtin_amdgcn_cvt_pkrtz(sx[i1], sy[i1]));
        half2v p3 = __builtin_bit_cast(half2v, __builtin_amdgcn_cvt_pkrtz(cx[i1], cy[i1]));
        half4v q0 = __builtin_shufflevector(p0, p1, 0, 1, 2, 3);
        half4v q1 = __builtin_shufflevector(p2, p3, 0, 1, 2, 3);
        bf[nt][kt] = __builtin_shufflevector(q0, q1, 0, 1, 2, 3, 4, 5, 6, 7);
      }
    }
  }

  f32x16 acc[2][NT];  // [mt][nt]
  half8 nbf[NT][4];   // [nt][kt]

  // transition: pkrtz raw acc -> packed-f16 lrelu (pk_mul + pk_max)
  auto transition = [&]() {
    #pragma unroll
    for (int mt = 0; mt < 2; ++mt)
      #pragma unroll
      for (int nt = 0; nt < NT; ++nt) {
        #pragma unroll
        for (int h = 0; h < 2; ++h) {
          half2v pp[4];
          #pragma unroll
          for (int p = 0; p < 4; ++p) {
            fp16x2 t = __builtin_amdgcn_cvt_pkrtz(acc[mt][nt][8 * h + 2 * p],
                                                  acc[mt][nt][8 * h + 2 * p + 1]);
            pp[p] = __builtin_bit_cast(half2v, t);
          }
          half4v q0 = __builtin_shufflevector(pp[0], pp[1], 0, 1, 2, 3);
          half4v q1 = __builtin_shufflevector(pp[2], pp[3], 0, 1, 2, 3);
          half8 f = __builtin_shufflevector(q0, q1, 0, 1, 2, 3, 4, 5, 6, 7);
          half8 f2 = f * (_Float16)0.2f;           // v_pk_mul_f16
          nbf[nt][2 * mt + h] = __builtin_elementwise_max(f, f2);  // v_pk_max_f16
        }
      }
  };

  auto init_acc = [&](const float* __restrict__ cb) {
    #pragma unroll
    for (int mt = 0; mt < 2; ++mt)
      #pragma unroll
      for (int g = 0; g < 4; ++g) {
        const float4 f = *(const float4*)(cb + 32 * mt + 8 * g + q4);
        #pragma unroll
        for (int nt = 0; nt < NT; ++nt) {
          acc[mt][nt][4 * g + 0] = f.x;
          acc[mt][nt][4 * g + 1] = f.y;
          acc[mt][nt][4 * g + 2] = f.z;
          acc[mt][nt][4 * g + 3] = f.w;
        }
      }
  };

  // ---- layer 1: K=32 (Kt=2) ----
  init_acc(cb1);
  #pragma unroll
  for (int kt = 0; kt < 2; ++kt) {
    half8 a0 = frags[FE_L1 + (0 * 2 + kt) * 64 + lane];
    half8 a1 = frags[FE_L1 + (1 * 2 + kt) * 64 + lane];
    #pragma unroll
    for (int nt = 0; nt < NT; ++nt) {
      acc[0][nt] = __builtin_amdgcn_mfma_f32_32x32x16_f16(a0, bf[nt][kt], acc[0][nt], 0, 0, 0);
      acc[1][nt] = __builtin_amdgcn_mfma_f32_32x32x16_f16(a1, bf[nt][kt], acc[1][nt], 0, 0, 0);
    }
  }
  transition();

  // ---- layers 2,3: K=64 (Kt=4) ----
  #pragma unroll
  for (int layer = 0; layer < 2; ++layer) {
    const int fe = layer == 0 ? FE_L2 : FE_L3;
    init_acc(layer == 0 ? cb2 : cb3);
    #pragma unroll
    for (int kt = 0; kt < 4; ++kt) {
      half8 a0 = frags[fe + (0 * 4 + kt) * 64 + lane];
      half8 a1 = frags[fe + (1 * 4 + kt) * 64 + lane];
      #pragma unroll
      for (int nt = 0; nt < NT; ++nt) {
        acc[0][nt] = __builtin_amdgcn_mfma_f32_32x32x16_f16(a0, nbf[nt][kt], acc[0][nt], 0, 0, 0);
        acc[1][nt] = __builtin_amdgcn_mfma_f32_32x32x16_f16(a1, nbf[nt][kt], acc[1][nt], 0, 0, 0);
      }
    }
    transition();
  }

  // ---- layer 4: 64 -> 4 ----
  f32x16 acc4[NT];
  {
    const float c0 = cb4[0], c1 = cb4[1], c2 = cb4[2], c3 = cb4[3];
    #pragma unroll
    for (int nt = 0; nt < NT; ++nt) {
      #pragma unroll
      for (int r = 0; r < 16; ++r) acc4[nt][r] = 0.f;
      if (!hi) {
        acc4[nt][0] = c0; acc4[nt][1] = c1; acc4[nt][2] = c2; acc4[nt][3] = c3;
      }
    }
  }
  #pragma unroll
  for (int kt = 0; kt < 4; ++kt) {
    half8 a0 = frags[FE_L4 + kt * 64 + lane];
    #pragma unroll
    for (int nt = 0; nt < NT; ++nt)
      acc4[nt] = __builtin_amdgcn_mfma_f32_32x32x16_f16(a0, nbf[nt][kt], acc4[nt], 0, 0, 0);
  }

  // epilogue: lanes 0..31 hold channels j=0..3 in regs 0..3
  if (!hi) {
    #pragma unroll
    for (int nt = 0; nt < NT; ++nt) {
      const float rad = sqrtf(cc[nt].x * cc[nt].x + cc[nt].y * cc[nt].y);
      const float tt = fmaxf(rad - 1.0f, 0.0f);
      const float m = 2.0f / (__expf(2.0f * tt) + 1.0f);
      out[px[nt]] = make_float4(acc4[nt][0] * m, acc4[nt][1] * m,
                                acc4[nt][2] * m, acc4[nt][3] * m);
    }
  }
}

extern "C" void kernel_launch(void* const* d_in, const int* in_sizes, int n_in,
                              void* d_out, int out_size, void* d_ws, size_t ws_size,
                              hipStream_t stream) {
  const float* coords = (const float*)d_in[0];
  const float* c      = (const float*)d_in[1];
  const float* fu     = (const float*)d_in[2];
  const float* w1     = (const float*)d_in[3];
  const float* b1     = (const float*)d_in[4];
  const float* w2     = (const float*)d_in[5];
  const float* b2     = (const float*)d_in[6];
  const float* w3     = (const float*)d_in[7];
  const float* b3     = (const float*)d_in[8];
  const float* w4     = (const float*)d_in[9];
  const float* b4     = (const float*)d_in[10];
  float* ws  = (float*)d_ws;
  float* out = (float*)d_out;

  int npix = in_sizes[0] / 2;  // 8*256*256 = 524288

  prep_kernel<<<56, 256, 0, stream>>>(c, fu, w1, b1, w2, b2, w3, b3, w4, b4, ws);
  decoder_main<<<npix / 512, 256, 0, stream>>>(
      (const float2*)coords, ws, (float4*)out);
}

// Round 12
// 95.761 us; speedup vs baseline: 1.0116x; 1.0116x over previous
//
#include <hip/hip_runtime.h>
#include <math.h>

// CoordinateDecoder via f16 MFMA (v_mfma_f32_32x32x16_f16).
// R12 = R9 (best config: NT=2, 4 waves/SIMD) + LDS fragment staging:
// R7/R9/R11 plateau at ~19-20us decoder across three VALU/ILP changes ->
// decoder is per-use load-latency bound (each layer's A-fragments loaded
// from global right before dependent MFMAs). Stage the 24.5KB fragment
// table into LDS once per block (6 coalesced dwordx4 copies/thread,
// overlapped with embedding compute), read via ds_read_b128.
// k-axis permutation trick: pi(16kt+8q+reg)=32(kt>>1)+16(kt&1)+8(reg>>2)+4q+(reg&3)
// makes C/D register layout == next layer's B-fragment layout (no cross-lane
// ops). sqrt(2) folded into next-layer weights; cond halves precomputed as
// fp32 accumulator-init biases by prep_kernel.

typedef _Float16 half2v __attribute__((ext_vector_type(2)));
typedef __fp16   fp16x2 __attribute__((ext_vector_type(2)));
typedef _Float16 half4v __attribute__((ext_vector_type(4)));
typedef _Float16 half8  __attribute__((ext_vector_type(8)));
typedef float f32x16 __attribute__((ext_vector_type(16)));

#define SCALE1 0.0790569415042094833f  // 1/sqrt(160)
#define SCALE2 0.0721687836487032206f  // 1/sqrt(192)
#define SQRT2F 1.41421356237309515f

// fragment region: half8 entries (16B each). tile entry = (mt*Kt+kt)*64+lane
#define FE_L1 0      // Mt=2, Kt=2 -> 4*64
#define FE_L2 256    // Mt=2, Kt=4 -> 8*64
#define FE_L3 768    // Mt=2, Kt=4 -> 8*64
#define FE_L4 1280   // Mt=1, Kt=4 -> 4*64 (rows j>=4 zeroed)
#define FE_TOT 1536  // 24576 B
#define OFF_CB1 6144   // [8][64] fp32 cond bias (incl b1)
#define OFF_CB2 6656
#define OFF_CB3 7168
#define OFF_CB4 7680   // [8][4]

__global__ __launch_bounds__(256) void prep_kernel(
    const float* __restrict__ c, const float* __restrict__ fu,
    const float* __restrict__ w1, const float* __restrict__ b1,
    const float* __restrict__ w2, const float* __restrict__ b2,
    const float* __restrict__ w3, const float* __restrict__ b3,
    const float* __restrict__ w4, const float* __restrict__ b4,
    float* __restrict__ ws)
{
  int t = blockIdx.x * 256 + threadIdx.x;
  if (t < 12288) {
    // weight A-fragment packing, f16
    _Float16* fr = (_Float16*)ws;
    int e, Ktm;
    const float* w; float scale; int stride; bool perm;
    if (t < 2048)       { e = t;         Ktm = 2; w = w1; scale = SCALE1;          stride = 160; perm = false; }
    else if (t < 6144)  { e = t - 2048;  Ktm = 4; w = w2; scale = SCALE2 * SQRT2F; stride = 192; perm = true;  }
    else if (t < 10240) { e = t - 6144;  Ktm = 4; w = w3; scale = SCALE2 * SQRT2F; stride = 192; perm = true;  }
    else                { e = t - 10240; Ktm = 4; w = w4; scale = SCALE2 * SQRT2F; stride = 192; perm = true;  }
    int til  = e >> 9;           // (mt*Kt+kt)
    int lane = (e >> 3) & 63;
    int r    = e & 7;            // reg within half8
    int q    = lane >> 5;
    int mt = til / Ktm, kt = til - mt * Ktm;
    int j = 32 * mt + (lane & 31);
    int k;
    if (perm) {
      k = 32 * (kt >> 1) + 16 * (kt & 1) + 8 * (r >> 2) + 4 * q + (r & 3);
    } else {
      k = 16 * kt + 8 * q + r;   // layer-1 embedding order (identity)
    }
    float val;
    if (t < 2048) {
      float mw = (fu[0] - (float)((k >> 2) + 1) * (1.0f / 9.0f)) * 9.0f;
      mw = fminf(fmaxf(mw, 0.0f), 1.0f);
      val = w[j * stride + k] * scale * mw;
    } else if (t >= 10240) {
      val = (j < 4) ? w[j * stride + k] * scale : 0.0f;  // mt==0 only
    } else {
      val = w[j * stride + k] * scale;
    }
    fr[t] = (_Float16)val;
  } else if (t < 12288 + 2048) {
    // per-(batch, output) conditioning dot products (fp32), wave-uniform
    int u = t - 12288;
    int grp = u >> 9;
    const float* wr; float bias; float scale; int outoff;
    int b, j;
    if (grp < 3) {
      b = (u & 511) >> 6; j = u & 63;
      if (grp == 0)      { wr = w1 + j * 160 + 32; bias = b1[j]; scale = SCALE1; outoff = OFF_CB1 + b * 64 + j; }
      else if (grp == 1) { wr = w2 + j * 192 + 64; bias = b2[j]; scale = SCALE2; outoff = OFF_CB2 + b * 64 + j; }
      else               { wr = w3 + j * 192 + 64; bias = b3[j]; scale = SCALE2; outoff = OFF_CB3 + b * 64 + j; }
    } else {
      int u2 = u - 1536;
      if (u2 >= 32) return;
      b = u2 >> 2; j = u2 & 3;
      wr = w4 + j * 192 + 64; bias = b4[j]; scale = SCALE2; outoff = OFF_CB4 + b * 4 + j;
    }
    const float4* wv = (const float4*)wr;
    const float4* cv = (const float4*)(c + b * 128);
    float4 s = make_float4(0.f, 0.f, 0.f, 0.f);
    #pragma unroll
    for (int k = 0; k < 32; ++k) {
      float4 a = wv[k], d = cv[k];
      s.x = fmaf(a.x, d.x, s.x);
      s.y = fmaf(a.y, d.y, s.y);
      s.z = fmaf(a.z, d.z, s.z);
      s.w = fmaf(a.w, d.w, s.w);
    }
    float dot = (s.x + s.y) + (s.z + s.w);
    ws[outoff] = fmaf(scale, dot, bias);
  }
}

__global__ __launch_bounds__(256, 4) void decoder_main(
    const float2* __restrict__ coords, const float* __restrict__ ws,
    float4* __restrict__ out)
{
  __shared__ __align__(16) _Float16 sfr_raw[FE_TOT * 8];  // 24576 B
  half8* __restrict__ sfr = (half8*)sfr_raw;

  const int tid  = threadIdx.x;
  const int lane = tid & 63;
  const int wave = tid >> 6;
  const int base = blockIdx.x * 256 + wave * 64;  // 64 px per wave
  const int b    = base >> 16;                    // batch image (block-uniform)
  const int col  = lane & 31;
  const bool hi  = lane >= 32;                    // q = lane>>5
  const int q4   = hi ? 4 : 0;

  // ---- stage fragment table global -> LDS (coalesced, 6 x 16B/thread) ----
  const half8* __restrict__ gfr = (const half8*)ws;
  #pragma unroll
  for (int i = 0; i < 6; ++i) {
    const int e = tid + 256 * i;
    sfr[e] = gfr[e];
  }

  const float* __restrict__ cb1 = ws + OFF_CB1 + b * 64;
  const float* __restrict__ cb2 = ws + OFF_CB2 + b * 64;
  const float* __restrict__ cb3 = ws + OFF_CB3 + b * 64;
  const float* __restrict__ cb4 = ws + OFF_CB4 + b * 4;

  const int p0 = base + col, p1 = base + 32 + col;
  const float2 cc0 = coords[p0];
  const float2 cc1 = coords[p1];

  // ---- layer-1 B fragments: sinusoidal embedding via double-angle chain --
  // lane needs freqs 2q+{0,1,4,5}: 2 transcendentals + 5 doublings per
  // axis-pixel. s'=2sc, c'=(c-s)(c+s). Packed f16 cvt via cvt_pkrtz.
  half8 bf[2][2];  // [nt][kt]
  {
    const float qm = hi ? 0.4f : 0.1f;  // 0.1 * 2^(2q)
    auto chain = [](float a, float* s, float* c) {
      float s0 = __sinf(a), c0 = __cosf(a);
      s[0] = s0; c[0] = c0;
      float s1 = 2.f * s0 * c0, c1 = (c0 - s0) * (c0 + s0);
      s[1] = s1; c[1] = c1;
      float s2 = 2.f * s1 * c1, c2 = (c1 - s1) * (c1 + s1);
      float s3 = 2.f * s2 * c2, c3 = (c2 - s2) * (c2 + s2);
      float s4 = 2.f * s3 * c3, c4 = (c3 - s3) * (c3 + s3);
      s[2] = s4; c[2] = c4;
      float s5 = 2.f * s4 * c4, c5 = (c4 - s4) * (c4 + s4);
      s[3] = s5; c[3] = c5;
    };
    #pragma unroll
    for (int nt = 0; nt < 2; ++nt) {
      const float2 cc = nt ? cc1 : cc0;
      float sx[4], cx[4], sy[4], cy[4];
      chain(cc.x * qm, sx, cx);
      chain(cc.y * qm, sy, cy);
      #pragma unroll
      for (int kt = 0; kt < 2; ++kt) {
        const int i0 = 2 * kt, i1 = 2 * kt + 1;
        half2v p0v = __builtin_bit_cast(half2v, __builtin_amdgcn_cvt_pkrtz(sx[i0], sy[i0]));
        half2v p1v = __builtin_bit_cast(half2v, __builtin_amdgcn_cvt_pkrtz(cx[i0], cy[i0]));
        half2v p2v = __builtin_bit_cast(half2v, __builtin_amdgcn_cvt_pkrtz(sx[i1], sy[i1]));
        half2v p3v = __builtin_bit_cast(half2v, __builtin_amdgcn_cvt_pkrtz(cx[i1], cy[i1]));
        half4v q0 = __builtin_shufflevector(p0v, p1v, 0, 1, 2, 3);
        half4v q1 = __builtin_shufflevector(p2v, p3v, 0, 1, 2, 3);
        bf[nt][kt] = __builtin_shufflevector(q0, q1, 0, 1, 2, 3, 4, 5, 6, 7);
      }
    }
  }

  __syncthreads();  // staging complete before first ds_read

  f32x16 acc[2][2];  // [mt][nt]
  half8 nbf[2][4];   // [nt][kt]

  // transition: pkrtz raw acc -> packed-f16 lrelu (pk_mul + pk_max)
  auto transition = [&]() {
    #pragma unroll
    for (int mt = 0; mt < 2; ++mt)
      #pragma unroll
      for (int nt = 0; nt < 2; ++nt) {
        #pragma unroll
        for (int h = 0; h < 2; ++h) {
          half2v pp[4];
          #pragma unroll
          for (int p = 0; p < 4; ++p) {
            fp16x2 t = __builtin_amdgcn_cvt_pkrtz(acc[mt][nt][8 * h + 2 * p],
                                                  acc[mt][nt][8 * h + 2 * p + 1]);
            pp[p] = __builtin_bit_cast(half2v, t);
          }
          half4v q0 = __builtin_shufflevector(pp[0], pp[1], 0, 1, 2, 3);
          half4v q1 = __builtin_shufflevector(pp[2], pp[3], 0, 1, 2, 3);
          half8 f = __builtin_shufflevector(q0, q1, 0, 1, 2, 3, 4, 5, 6, 7);
          half8 f2 = f * (_Float16)0.2f;           // v_pk_mul_f16
          nbf[nt][2 * mt + h] = __builtin_elementwise_max(f, f2);  // v_pk_max_f16
        }
      }
  };

  auto init_acc = [&](const float* __restrict__ cb) {
    #pragma unroll
    for (int mt = 0; mt < 2; ++mt)
      #pragma unroll
      for (int g = 0; g < 4; ++g) {
        const float4 f = *(const float4*)(cb + 32 * mt + 8 * g + q4);
        #pragma unroll
        for (int nt = 0; nt < 2; ++nt) {
          acc[mt][nt][4 * g + 0] = f.x;
          acc[mt][nt][4 * g + 1] = f.y;
          acc[mt][nt][4 * g + 2] = f.z;
          acc[mt][nt][4 * g + 3] = f.w;
        }
      }
  };

  // ---- layer 1: K=32 (Kt=2) ----
  init_acc(cb1);
  #pragma unroll
  for (int kt = 0; kt < 2; ++kt) {
    half8 a0 = sfr[FE_L1 + (0 * 2 + kt) * 64 + lane];
    half8 a1 = sfr[FE_L1 + (1 * 2 + kt) * 64 + lane];
    acc[0][0] = __builtin_amdgcn_mfma_f32_32x32x16_f16(a0, bf[0][kt], acc[0][0], 0, 0, 0);
    acc[0][1] = __builtin_amdgcn_mfma_f32_32x32x16_f16(a0, bf[1][kt], acc[0][1], 0, 0, 0);
    acc[1][0] = __builtin_amdgcn_mfma_f32_32x32x16_f16(a1, bf[0][kt], acc[1][0], 0, 0, 0);
    acc[1][1] = __builtin_amdgcn_mfma_f32_32x32x16_f16(a1, bf[1][kt], acc[1][1], 0, 0, 0);
  }
  transition();

  // ---- layers 2,3: K=64 (Kt=4) ----
  #pragma unroll
  for (int layer = 0; layer < 2; ++layer) {
    const int fe = layer == 0 ? FE_L2 : FE_L3;
    init_acc(layer == 0 ? cb2 : cb3);
    #pragma unroll
    for (int kt = 0; kt < 4; ++kt) {
      half8 a0 = sfr[fe + (0 * 4 + kt) * 64 + lane];
      half8 a1 = sfr[fe + (1 * 4 + kt) * 64 + lane];
      acc[0][0] = __builtin_amdgcn_mfma_f32_32x32x16_f16(a0, nbf[0][kt], acc[0][0], 0, 0, 0);
      acc[0][1] = __builtin_amdgcn_mfma_f32_32x32x16_f16(a0, nbf[1][kt], acc[0][1], 0, 0, 0);
      acc[1][0] = __builtin_amdgcn_mfma_f32_32x32x16_f16(a1, nbf[0][kt], acc[1][0], 0, 0, 0);
      acc[1][1] = __builtin_amdgcn_mfma_f32_32x32x16_f16(a1, nbf[1][kt], acc[1][1], 0, 0, 0);
    }
    transition();
  }

  // ---- layer 4: 64 -> 4 ----
  f32x16 acc4[2];
  {
    const float c0 = cb4[0], c1 = cb4[1], c2 = cb4[2], c3 = cb4[3];
    #pragma unroll
    for (int r = 0; r < 16; ++r) { acc4[0][r] = 0.f; acc4[1][r] = 0.f; }
    if (!hi) {
      acc4[0][0] = c0; acc4[0][1] = c1; acc4[0][2] = c2; acc4[0][3] = c3;
      acc4[1][0] = c0; acc4[1][1] = c1; acc4[1][2] = c2; acc4[1][3] = c3;
    }
  }
  #pragma unroll
  for (int kt = 0; kt < 4; ++kt) {
    half8 a0 = sfr[FE_L4 + kt * 64 + lane];
    acc4[0] = __builtin_amdgcn_mfma_f32_32x32x16_f16(a0, nbf[0][kt], acc4[0], 0, 0, 0);
    acc4[1] = __builtin_amdgcn_mfma_f32_32x32x16_f16(a0, nbf[1][kt], acc4[1], 0, 0, 0);
  }

  // epilogue: lanes 0..31 hold channels j=0..3 in regs 0..3
  if (!hi) {
    #pragma unroll
    for (int nt = 0; nt < 2; ++nt) {
      const float2 cc = nt ? cc1 : cc0;
      const float rad = sqrtf(cc.x * cc.x + cc.y * cc.y);
      const float tt = fmaxf(rad - 1.0f, 0.0f);
      const float m = 2.0f / (__expf(2.0f * tt) + 1.0f);
      out[nt ? p1 : p0] = make_float4(acc4[nt][0] * m, acc4[nt][1] * m,
                                      acc4[nt][2] * m, acc4[nt][3] * m);
    }
  }
}

extern "C" void kernel_launch(void* const* d_in, const int* in_sizes, int n_in,
                              void* d_out, int out_size, void* d_ws, size_t ws_size,
                              hipStream_t stream) {
  const float* coords = (const float*)d_in[0];
  const float* c      = (const float*)d_in[1];
  const float* fu     = (const float*)d_in[2];
  const float* w1     = (const float*)d_in[3];
  const float* b1     = (const float*)d_in[4];
  const float* w2     = (const float*)d_in[5];
  const float* b2     = (const float*)d_in[6];
  const float* w3     = (const float*)d_in[7];
  const float* b3     = (const float*)d_in[8];
  const float* w4     = (const float*)d_in[9];
  const float* b4     = (const float*)d_in[10];
  float* ws  = (float*)d_ws;
  float* out = (float*)d_out;

  int npix = in_sizes[0] / 2;  // 8*256*256 = 524288

  prep_kernel<<<56, 256, 0, stream>>>(c, fu, w1, b1, w2, b2, w3, b3, w4, b4, ws);
  decoder_main<<<npix / 256, 256, 0, stream>>>(
      (const float2*)coords, ws, (float4*)out);
}